// Round 1
// baseline (57.810 us; speedup 1.0000x reference)
//
#include <hip/hip_runtime.h>
#include <hip/hip_bf16.h>

#define DIM 256
#define NAGENT 64
#define NBATCH 256

typedef __bf16 bf16_t;
typedef bf16_t bf16x8 __attribute__((ext_vector_type(8)));
typedef float f32x4 __attribute__((ext_vector_type(4)));

// prep1: Whs = W_head @ W_sum  (fp32), u = W_head @ b_sum + b_head
__global__ __launch_bounds__(256) void prep1_kernel(
    const float* __restrict__ Wh, const float* __restrict__ Ws,
    const float* __restrict__ bs, const float* __restrict__ bh,
    float* __restrict__ Whs, float* __restrict__ u) {
  const int i = blockIdx.x, j = threadIdx.x;
  const float* whrow = Wh + i * DIM;
  float acc = 0.f;
#pragma unroll 4
  for (int k = 0; k < DIM; ++k) acc += whrow[k] * Ws[k * DIM + j];
  Whs[i * DIM + j] = acc;

  __shared__ float red[256];
  red[j] = whrow[j] * bs[j];
  __syncthreads();
  for (int s = 128; s > 0; s >>= 1) {
    if (j < s) red[j] += red[j + s];
    __syncthreads();
  }
  if (j == 0) u[i] = red[0] + bh[i];
}

// prep2: Wc = bf16(Whs @ W_act), bc = Whs @ b_act + u
__global__ __launch_bounds__(256) void prep2_kernel(
    const float* __restrict__ Whs, const float* __restrict__ Wa,
    const float* __restrict__ ba, const float* __restrict__ u,
    bf16_t* __restrict__ Wc, float* __restrict__ bc) {
  const int i = blockIdx.x, j = threadIdx.x;
  const float* wr = Whs + i * DIM;
  float acc = 0.f;
#pragma unroll 4
  for (int k = 0; k < DIM; ++k) acc += wr[k] * Wa[k * DIM + j];
  Wc[i * DIM + j] = (bf16_t)acc;

  __shared__ float red[256];
  red[j] = wr[j] * ba[j];
  __syncthreads();
  for (int s = 128; s > 0; s >>= 1) {
    if (j < s) red[j] += red[j + s];
    __syncthreads();
  }
  if (j == 0) bc[i] = red[0] + u[i];
}

// fused main: per-batch column sums -> g (bf16, LDS, swizzled) -> MFMA GEMM
// out[b*64+j, d] = relu( sum_k g[j,k] * Wc[d,k] + bc[d] )
__global__ __launch_bounds__(512) void fused_kernel(
    const float* __restrict__ h, const bf16_t* __restrict__ Wc,
    const float* __restrict__ bc, float* __restrict__ out) {
  const int b = blockIdx.x;
  const int t = threadIdx.x;

  __shared__ __align__(16) bf16_t g[NAGENT * DIM];  // 32 KB, XOR-swizzled
  __shared__ float ps[512];

  const float* hb = h + (size_t)b * NAGENT * DIM;
  const int c = t & 255;       // column 0..255
  const int half = t >> 8;     // 0: rows 0..31, 1: rows 32..63

  // phase 0: partial column sums over this half's 32 rows
  float s = 0.f;
#pragma unroll
  for (int i = 0; i < 32; ++i) s += hb[(half * 32 + i) * DIM + c];
  ps[t] = s;
  __syncthreads();
  const float hs = ps[c] + ps[256 + c];

  // phase 1: g[row][k] = (hs - h[row][k]) / 63, store bf16 with XOR swizzle
  const float inv = 1.0f / 63.0f;
#pragma unroll
  for (int i = 0; i < 32; ++i) {
    const int row = half * 32 + i;
    const float v = (hs - hb[row * DIM + c]) * inv;
    g[row * DIM + (c ^ ((row & 7) << 3))] = (bf16_t)v;
  }
  __syncthreads();

  // phase 2: GEMM. 8 waves: wave (wr,wc) owns rows wr*16..+15, cols wc*128..+127
  const int w = t >> 6, lane = t & 63;
  const int wr = w >> 1, wcol = w & 1;
  const int lrow = lane & 15, lgrp = lane >> 4;

  f32x4 acc[8];
#pragma unroll
  for (int nt = 0; nt < 8; ++nt) acc[nt] = (f32x4){0.f, 0.f, 0.f, 0.f};

  const int arow = wr * 16 + lrow;
  const int abase = arow * DIM;
  const int aswz = (arow & 7) << 3;

#pragma unroll
  for (int kk = 0; kk < 8; ++kk) {
    const int k0 = kk * 32 + lgrp * 8;
    const bf16x8 afrag = *(const bf16x8*)&g[abase + (k0 ^ aswz)];
#pragma unroll
    for (int nt = 0; nt < 8; ++nt) {
      const int col = wcol * 128 + nt * 16 + lrow;
      const bf16x8 bfrag = *(const bf16x8*)&Wc[col * DIM + k0];
      acc[nt] = __builtin_amdgcn_mfma_f32_16x16x32_bf16(afrag, bfrag, acc[nt], 0, 0, 0);
    }
  }

  // epilogue: C/D layout col=lane&15, row=(lane>>4)*4+reg  [m89-verified]
  float* ob = out + (size_t)b * NAGENT * DIM;
#pragma unroll
  for (int nt = 0; nt < 8; ++nt) {
    const int col = wcol * 128 + nt * 16 + lrow;
    const float bcv = bc[col];
#pragma unroll
    for (int r = 0; r < 4; ++r) {
      const int row = wr * 16 + lgrp * 4 + r;
      const float v = acc[nt][r] + bcv;
      ob[row * DIM + col] = v > 0.f ? v : 0.f;
    }
  }
}

extern "C" void kernel_launch(void* const* d_in, const int* in_sizes, int n_in,
                              void* d_out, int out_size, void* d_ws, size_t ws_size,
                              hipStream_t stream) {
  const float* h  = (const float*)d_in[0];  // hidden_state (16384,256)
  const float* Wa = (const float*)d_in[1];  // W_act (256,256)
  const float* ba = (const float*)d_in[2];  // b_act (256,)
  const float* Ws = (const float*)d_in[3];  // W_sum (256,256)
  const float* bs = (const float*)d_in[4];  // b_sum (256,)
  const float* Wh = (const float*)d_in[5];  // W_head (256,256)
  const float* bh = (const float*)d_in[6];  // b_head (256,)
  float* out = (float*)d_out;

  // workspace layout
  char* ws = (char*)d_ws;
  float*  Whs = (float*)ws;                    // 256*256*4 = 256 KB
  bf16_t* Wc  = (bf16_t*)(ws + 256 * 1024);    // 256*256*2 = 128 KB
  float*  u   = (float*)(ws + 384 * 1024);     // 1 KB
  float*  bcv = (float*)(ws + 388 * 1024);     // 1 KB

  prep1_kernel<<<256, 256, 0, stream>>>(Wh, Ws, bs, bh, Whs, u);
  prep2_kernel<<<256, 256, 0, stream>>>(Whs, Wa, ba, u, Wc, bcv);
  fused_kernel<<<NBATCH, 512, 0, stream>>>(h, Wc, bcv, out);
}

// Round 2
// 35.907 us; speedup vs baseline: 1.6100x; 1.6100x over previous
//
#include <hip/hip_runtime.h>
#include <hip/hip_bf16.h>

#define DIM 256
#define NAGENT 64
#define NBATCH 256

typedef __bf16 bf16_t;
typedef bf16_t bf16x4 __attribute__((ext_vector_type(4)));
typedef bf16_t bf16x8 __attribute__((ext_vector_type(8)));
typedef float f32x4 __attribute__((ext_vector_type(4)));

// Fused prep: Wc = bf16(Wh @ Ws @ Wa)  (row-major, [out_d][in_d]),
//             bc = Wh @ (Ws @ ba + bs) + bh
// computed as: t1 = Wh_row @ Ws ;  Wc_row = t1 @ Wa ;
//              bc_i = dot(t1, ba) + dot(Wh_row, bs) + bh_i
// grid 64 blocks x 1024 threads; each block does 4 consecutive output rows.
// Thread (q = t>>8, j = t&255): K-quarter q, column j. 4 rows share each load.
__global__ __launch_bounds__(1024) void prep_kernel(
    const float* __restrict__ Wh, const float* __restrict__ Ws,
    const float* __restrict__ Wa, const float* __restrict__ ba,
    const float* __restrict__ bs, const float* __restrict__ bh,
    bf16_t* __restrict__ Wc, float* __restrict__ bc) {
  const int i0 = blockIdx.x * 4;
  const int t = threadIdx.x;
  const int j = t & 255;
  const int q = t >> 8;

  __shared__ float whl[4][256];      // 4 Wh rows
  __shared__ float t1[4][256];       // intermediate Whs rows
  __shared__ float part[4][4][256];  // [q][r][j] partial sums
  __shared__ float red[1024];

  whl[q][j] = Wh[(i0 + q) * DIM + j];
  __syncthreads();

  // stage 1: t1[r][j] = sum_k whl[r][k] * Ws[k][j], k in quarter q
  {
    float a0 = 0.f, a1 = 0.f, a2 = 0.f, a3 = 0.f;
    const float* wsp = Ws + (q * 64) * DIM + j;
    const float* w0 = &whl[0][q * 64];
    const float* w1 = &whl[1][q * 64];
    const float* w2 = &whl[2][q * 64];
    const float* w3 = &whl[3][q * 64];
#pragma unroll 8
    for (int k = 0; k < 64; ++k) {
      const float wv = wsp[k * DIM];
      a0 += w0[k] * wv; a1 += w1[k] * wv; a2 += w2[k] * wv; a3 += w3[k] * wv;
    }
    part[q][0][j] = a0; part[q][1][j] = a1; part[q][2][j] = a2; part[q][3][j] = a3;
  }
  __syncthreads();
  // thread (q,j) reduces row r=q
  t1[q][j] = part[0][q][j] + part[1][q][j] + part[2][q][j] + part[3][q][j];
  __syncthreads();

  // stage 2: Wc[r][j] = bf16( sum_k t1[r][k] * Wa[k][j] )
  {
    float a0 = 0.f, a1 = 0.f, a2 = 0.f, a3 = 0.f;
    const float* wap = Wa + (q * 64) * DIM + j;
    const float* u0 = &t1[0][q * 64];
    const float* u1 = &t1[1][q * 64];
    const float* u2 = &t1[2][q * 64];
    const float* u3 = &t1[3][q * 64];
#pragma unroll 8
    for (int k = 0; k < 64; ++k) {
      const float wv = wap[k * DIM];
      a0 += u0[k] * wv; a1 += u1[k] * wv; a2 += u2[k] * wv; a3 += u3[k] * wv;
    }
    red[t] = t1[q][j] * ba[j] + whl[q][j] * bs[j];  // bias partial for row q
    __syncthreads();  // covers part reads from stage-1 reduction done above
    part[q][0][j] = a0; part[q][1][j] = a1; part[q][2][j] = a2; part[q][3][j] = a3;
  }
  __syncthreads();
  {
    const float w = part[0][q][j] + part[1][q][j] + part[2][q][j] + part[3][q][j];
    Wc[(i0 + q) * DIM + j] = (bf16_t)w;
  }
  // bias: tree-reduce red within each 256-thread q-group
  for (int s = 128; s > 0; s >>= 1) {
    if (j < s) red[q * 256 + j] += red[q * 256 + j + s];
    __syncthreads();
  }
  if (j == 0) bc[i0 + q] = red[q * 256] + bh[i0 + q];
}

// Fused main: out[b*64+j, d] = relu( sum_k g[j,k] * Wc[d,k] + bc[d] )
// where g[j,k] = (sum_i h[b,i,k] - h[b,j,k]) / 63.
// h is read exactly ONCE (float4); g built from registers into swizzled LDS.
__global__ __launch_bounds__(512) void fused_kernel(
    const float* __restrict__ h, const bf16_t* __restrict__ Wc,
    const float* __restrict__ bc, float* __restrict__ out) {
  const int b = blockIdx.x;
  const int t = threadIdx.x;

  __shared__ __align__(16) bf16_t g[NAGENT * DIM];  // 32 KB, XOR-swizzled
  __shared__ f32x4 ps[8][64];                       // 8 KB

  const float* hb = h + (size_t)b * NAGENT * DIM;
  const int cg = t & 63;   // col-group: cols cg*4 .. cg*4+3
  const int rg = t >> 6;   // row-group: rows rg*8 .. rg*8+7

  // single pass over h: keep 8 rows x 4 cols in registers
  f32x4 v[8];
  f32x4 s4 = {0.f, 0.f, 0.f, 0.f};
#pragma unroll
  for (int i = 0; i < 8; ++i) {
    v[i] = *(const f32x4*)&hb[(rg * 8 + i) * DIM + cg * 4];
    s4 += v[i];
  }
  ps[rg][cg] = s4;
  __syncthreads();
  f32x4 hs = ps[0][cg];
#pragma unroll
  for (int r = 1; r < 8; ++r) hs += ps[r][cg];

  const float inv = 1.0f / 63.0f;
#pragma unroll
  for (int i = 0; i < 8; ++i) {
    const int row = rg * 8 + i;
    const f32x4 gv = (hs - v[i]) * inv;
    bf16x4 gb;
    gb[0] = (bf16_t)gv[0]; gb[1] = (bf16_t)gv[1];
    gb[2] = (bf16_t)gv[2]; gb[3] = (bf16_t)gv[3];
    *(bf16x4*)&g[row * DIM + ((cg * 4) ^ ((row & 7) << 3))] = gb;
  }
  __syncthreads();

  // GEMM: 8 waves, wave (wr,wcol) owns rows wr*16..+15, cols wcol*128..+127
  const int w = t >> 6, lane = t & 63;
  const int wr = w >> 1, wcol = w & 1;
  const int lrow = lane & 15, lgrp = lane >> 4;

  f32x4 acc[8];
#pragma unroll
  for (int nt = 0; nt < 8; ++nt) acc[nt] = (f32x4){0.f, 0.f, 0.f, 0.f};

  const int arow = wr * 16 + lrow;
  const int abase = arow * DIM;
  const int aswz = (arow & 7) << 3;

#pragma unroll
  for (int kk = 0; kk < 8; ++kk) {
    const int k0 = kk * 32 + lgrp * 8;
    const bf16x8 afrag = *(const bf16x8*)&g[abase + (k0 ^ aswz)];
#pragma unroll
    for (int nt = 0; nt < 8; ++nt) {
      const int col = wcol * 128 + nt * 16 + lrow;
      const bf16x8 bfrag = *(const bf16x8*)&Wc[col * DIM + k0];
      acc[nt] = __builtin_amdgcn_mfma_f32_16x16x32_bf16(afrag, bfrag, acc[nt], 0, 0, 0);
    }
  }

  // epilogue: C/D layout col=lane&15, row=(lane>>4)*4+reg  [m89-verified]
  float* ob = out + (size_t)b * NAGENT * DIM;
#pragma unroll
  for (int nt = 0; nt < 8; ++nt) {
    const int col = wcol * 128 + nt * 16 + lrow;
    const float bcv = bc[col];
#pragma unroll
    for (int r = 0; r < 4; ++r) {
      const int row = wr * 16 + lgrp * 4 + r;
      const float val = acc[nt][r] + bcv;
      ob[row * DIM + col] = val > 0.f ? val : 0.f;
    }
  }
}

extern "C" void kernel_launch(void* const* d_in, const int* in_sizes, int n_in,
                              void* d_out, int out_size, void* d_ws, size_t ws_size,
                              hipStream_t stream) {
  const float* h  = (const float*)d_in[0];  // hidden_state (16384,256)
  const float* Wa = (const float*)d_in[1];  // W_act (256,256)
  const float* ba = (const float*)d_in[2];  // b_act (256,)
  const float* Ws = (const float*)d_in[3];  // W_sum (256,256)
  const float* bs = (const float*)d_in[4];  // b_sum (256,)
  const float* Wh = (const float*)d_in[5];  // W_head (256,256)
  const float* bh = (const float*)d_in[6];  // b_head (256,)
  float* out = (float*)d_out;

  char* ws = (char*)d_ws;
  bf16_t* Wc  = (bf16_t*)ws;                 // 128 KB
  float*  bcv = (float*)(ws + 128 * 1024);   // 1 KB

  prep_kernel<<<64, 1024, 0, stream>>>(Wh, Ws, Wa, ba, bs, bh, Wc, bcv);
  fused_kernel<<<NBATCH, 512, 0, stream>>>(h, Wc, bcv, out);
}